// Round 3
// baseline (548.316 us; speedup 1.0000x reference)
//
#include <hip/hip_runtime.h>
#include <hip/hip_bf16.h>
#include <math.h>

// ---------------------------------------------------------------------------
// Attention_17231408791684: x->QKV (bias) -> RoPE -> sliding-window(128)
// causal attention w/ sinks -> O-proj (bias).
// B=1 S=2048 DIM=2880 NH=64 NKV=8 HD=64
// Round 3: dtype-agnostic. Device-side detector decides whether d_in buffers
// are bf16 or f32; two templated pipelines are launched, gated on the flag.
// Intermediates always bf16; output dtype follows input dtype.
// ---------------------------------------------------------------------------

typedef __bf16 bf16x8 __attribute__((ext_vector_type(8)));
typedef float  f32x4  __attribute__((ext_vector_type(4)));

#define MFMA_BF16(a,b,c) __builtin_amdgcn_mfma_f32_16x16x32_bf16((a),(b),(c),0,0,0)

// load 8 consecutive elements as bf16x8, from either bf16 or f32 memory
__device__ __forceinline__ bf16x8 ld8(const __bf16* p) {
    return *(const bf16x8*)p;
}
__device__ __forceinline__ bf16x8 ld8(const float* p) {
    f32x4 a = *(const f32x4*)p;
    f32x4 b = *(const f32x4*)(p + 4);
    bf16x8 r;
#pragma unroll
    for (int t = 0; t < 4; t++) { r[t] = (__bf16)a[t]; r[t + 4] = (__bf16)b[t]; }
    return r;
}

// ---------------------------------------------------------------------------
// dtype detector: x ~ N(0,1). As bf16, max|first 256| < ~6. If the buffer is
// f32, odd u16s are mantissa halves -> uniform exponents -> huge/NaN values.
// flag: 0 = bf16 buffers, 1 = f32 buffers.
// ---------------------------------------------------------------------------
__global__ void detect_kernel(const unsigned short* __restrict__ xs,
                              int* __restrict__ flag)
{
    int lane = threadIdx.x;            // 64 threads
    bool bad = false;
#pragma unroll
    for (int t = 0; t < 4; t++) {
        unsigned int w = ((unsigned int)xs[lane * 4 + t]) << 16;
        float v = __uint_as_float(w);
        if (!(fabsf(v) <= 1.0e6f)) bad = true;   // also catches NaN
    }
    unsigned long long any = __ballot(bad);
    if (lane == 0) *flag = (any != 0ULL) ? 1 : 0;
}

// ---------------------------------------------------------------------------
// NT GEMM: C[M,N] = A[M,K] * W[N,K]^T + bias. 128x128 tile, BK=32, 256 thr
// (4 waves as 2x2 of 64x64). LDS stride 40 kills ds_read_b128 conflicts.
// ---------------------------------------------------------------------------
template <typename TA, typename TW, typename TO>
__device__ __forceinline__ void gemm_block(
    const TA* __restrict__ A, const TW* __restrict__ W,
    const TW* __restrict__ bias, TO* __restrict__ C,
    int N, int K, int m0, int n0, __bf16* As, __bf16* Bs)
{
    const int tid  = threadIdx.x;
    const int lane = tid & 63;
    const int wv   = tid >> 6;
    const int wm   = (wv >> 1) * 64;
    const int wn   = (wv & 1) * 64;
    const int quad = lane >> 4;
    const int c    = lane & 15;

    const int arow = tid >> 2;          // 0..63
    const int acol = (tid & 3) * 8;     // 0,8,16,24

    int br0 = n0 + arow;      if (br0 > N - 1) br0 = N - 1;   // N=2880 tail clamp
    int br1 = n0 + 64 + arow; if (br1 > N - 1) br1 = N - 1;
    const TA* pa0 = A + (size_t)(m0 + arow) * K + acol;
    const TA* pa1 = A + (size_t)(m0 + 64 + arow) * K + acol;
    const TW* pb0 = W + (size_t)br0 * K + acol;
    const TW* pb1 = W + (size_t)br1 * K + acol;

    f32x4 acc[4][4];
#pragma unroll
    for (int i = 0; i < 4; i++)
#pragma unroll
        for (int j = 0; j < 4; j++) acc[i][j] = (f32x4){0.f, 0.f, 0.f, 0.f};

    for (int kk = 0; kk < K; kk += 32) {
        bf16x8 a0 = ld8(pa0 + kk);
        bf16x8 a1 = ld8(pa1 + kk);
        bf16x8 b0 = ld8(pb0 + kk);
        bf16x8 b1 = ld8(pb1 + kk);
        __syncthreads();                       // prior iter LDS reads done
        *(bf16x8*)&As[arow * 40 + acol]        = a0;
        *(bf16x8*)&As[(arow + 64) * 40 + acol] = a1;
        *(bf16x8*)&Bs[arow * 40 + acol]        = b0;
        *(bf16x8*)&Bs[(arow + 64) * 40 + acol] = b1;
        __syncthreads();                       // tile visible
        bf16x8 af[4], bfv[4];
#pragma unroll
        for (int i = 0; i < 4; i++)
            af[i] = *(const bf16x8*)&As[(wm + i * 16 + c) * 40 + quad * 8];
#pragma unroll
        for (int j = 0; j < 4; j++)
            bfv[j] = *(const bf16x8*)&Bs[(wn + j * 16 + c) * 40 + quad * 8];
#pragma unroll
        for (int i = 0; i < 4; i++)
#pragma unroll
            for (int j = 0; j < 4; j++)
                acc[i][j] = MFMA_BF16(af[i], bfv[j], acc[i][j]);
    }

    // epilogue: D row = quad*4+r, col = c (m89-verified layout)
#pragma unroll
    for (int j = 0; j < 4; j++) {
        int col = n0 + wn + j * 16 + c;
        if (col >= N) continue;
        float bv = (float)bias[col];
#pragma unroll
        for (int i = 0; i < 4; i++) {
            int row = m0 + wm + i * 16 + quad * 4;
#pragma unroll
            for (int r = 0; r < 4; r++)
                C[(size_t)(row + r) * N + col] = (TO)(acc[i][j][r] + bv);
        }
    }
}

// Fused QKV: grid (16, 40); by<32 -> q (N=4096), by<36 -> k, else v (N=512)
template <typename T>
__global__ __launch_bounds__(256) void qkv_kernel(
    const T* __restrict__ x,
    const T* __restrict__ wq, const T* __restrict__ bq,
    const T* __restrict__ wk, const T* __restrict__ bk,
    const T* __restrict__ wv, const T* __restrict__ bv,
    __bf16* __restrict__ qo, __bf16* __restrict__ ko, __bf16* __restrict__ vo,
    const int* __restrict__ flag, int want)
{
    if (*flag != want) return;
    __shared__ __align__(16) __bf16 As[5120], Bs[5120];
    const int by = blockIdx.y;
    const T *W, *bias; __bf16* C; int N, n0;
    if (by < 32)      { W = wq; bias = bq; C = qo; N = 4096; n0 = by * 128; }
    else if (by < 36) { W = wk; bias = bk; C = ko; N = 512;  n0 = (by - 32) * 128; }
    else              { W = wv; bias = bv; C = vo; N = 512;  n0 = (by - 36) * 128; }
    gemm_block<T, T, __bf16>(x, W, bias, C, N, 2880, blockIdx.x * 128, n0, As, Bs);
}

// O-proj: grid (16, 23): out[2048,2880] = AB[2048,4096] * wo[2880,4096]^T + bo
template <typename T>
__global__ __launch_bounds__(256) void oproj_kernel(
    const __bf16* __restrict__ a, const T* __restrict__ w,
    const T* __restrict__ b, T* __restrict__ c,
    const int* __restrict__ flag, int want)
{
    if (*flag != want) return;
    __shared__ __align__(16) __bf16 As[5120], Bs[5120];
    gemm_block<__bf16, T, T>(a, w, b, c, 2880, 4096,
                             blockIdx.x * 128, blockIdx.y * 128, As, Bs);
}

// ---------------------------------------------------------------------------
// RoPE in-place on qb[2048,64,64] / kb[2048,8,64] (always bf16).
// rope_cache[s] = [cos(64) | sin(64)], halves duplicated.
// thread = (s, head 0..71, dgroup 0..3): d in [d0,d0+8) and [d0+32,d0+40)
// ---------------------------------------------------------------------------
template <typename T>
__global__ __launch_bounds__(256) void rope_kernel(
    __bf16* __restrict__ qb, __bf16* __restrict__ kb,
    const T* __restrict__ rope, const int* __restrict__ flag, int want)
{
    if (*flag != want) return;
    int idx  = blockIdx.x * 256 + threadIdx.x;   // 2048*72*4, exact grid
    int dg   = idx & 3;
    int head = (idx >> 2) % 72;
    int s    = (idx >> 2) / 72;
    __bf16* p = (head < 64) ? (qb + (size_t)s * 4096 + head * 64)
                            : (kb + (size_t)s * 512 + (size_t)(head - 64) * 64);
    int d0 = dg * 8;
    bf16x8 x1 = *(bf16x8*)(p + d0);
    bf16x8 x2 = *(bf16x8*)(p + d0 + 32);
    bf16x8 cs = ld8(rope + (size_t)s * 128 + d0);
    bf16x8 sn = ld8(rope + (size_t)s * 128 + 64 + d0);
    bf16x8 o1, o2;
#pragma unroll
    for (int t = 0; t < 8; t++) {
        float cc = (float)cs[t], si = (float)sn[t];
        float a = (float)x1[t], b = (float)x2[t];
        o1[t] = (__bf16)(a * cc - b * si);
        o2[t] = (__bf16)(b * cc + a * si);
    }
    *(bf16x8*)(p + d0)      = o1;
    *(bf16x8*)(p + d0 + 32) = o2;
}

// ---------------------------------------------------------------------------
// Attention, IN-PLACE on q (each block reads exactly the q region it later
// overwrites). block = (64-query tile, head); wave w owns q rows
// [w*16, w*16+16) x all 192 staged keys (k0 = i0-128 covers the window).
// Softmax stats wave-local via shfl over the 16-lane c group.
// LDS: Qs[64][72]@0, Ks[192][72]@9216, Vt[64][208]@36864; P overlays @0.
// ---------------------------------------------------------------------------
template <typename T>
__global__ __launch_bounds__(256) void attn_kernel(
    __bf16* __restrict__ q, const __bf16* __restrict__ k,
    const __bf16* __restrict__ v, const T* __restrict__ sinks,
    const int* __restrict__ flag, int want)
{
    if (*flag != want) return;
    __shared__ __align__(16) char smem[63488];
    __bf16* Qs = (__bf16*)smem;                 // [64][72]
    __bf16* Ks = (__bf16*)(smem + 9216);        // [192][72]
    __bf16* Vt = (__bf16*)(smem + 36864);       // [64][208]
    __bf16* P  = (__bf16*)smem;                 // [64][208] overlay (post-QK^T)

    const int tid = threadIdx.x, lane = tid & 63, w = tid >> 6;
    const int quad = lane >> 4, c = lane & 15;
    const int i0 = blockIdx.x * 64;
    const int h  = blockIdx.y;
    const int kvh = h >> 3;
    const int k0 = i0 - 128;

    // ---- stage Q, K (stride 72) and V transposed (stride 208)
    {
        const int row = tid >> 3;           // 0..31
        const int col = (tid & 7) * 8;      // 0..56
#pragma unroll
        for (int it = 0; it < 2; it++) {
            int r2 = row + it * 32;
            bf16x8 t = *(const bf16x8*)(q + (size_t)(i0 + r2) * 4096 + h * 64 + col);
            *(bf16x8*)&Qs[r2 * 72 + col] = t;
        }
#pragma unroll
        for (int it = 0; it < 6; it++) {
            int r2 = row + it * 32;
            int j = k0 + r2; if (j < 0) j = 0;
            bf16x8 t = *(const bf16x8*)(k + (size_t)j * 512 + kvh * 64 + col);
            *(bf16x8*)&Ks[r2 * 72 + col] = t;
        }
        const int vrow = tid & 31;
        const int d0 = (tid >> 5) * 8;
#pragma unroll
        for (int it = 0; it < 6; it++) {
            int r2 = vrow + it * 32;
            int j = k0 + r2; if (j < 0) j = 0;
            bf16x8 t = *(const bf16x8*)(v + (size_t)j * 512 + kvh * 64 + d0);
#pragma unroll
            for (int u = 0; u < 8; u++) Vt[(d0 + u) * 208 + r2] = t[u];
        }
    }
    __syncthreads();

    // ---- QK^T: wave w -> its 16 q rows x 192 keys (12 key tiles)
    f32x4 acc[12];
#pragma unroll
    for (int j = 0; j < 12; j++) acc[j] = (f32x4){0.f, 0.f, 0.f, 0.f};
#pragma unroll
    for (int kt = 0; kt < 2; kt++) {
        bf16x8 af = *(const bf16x8*)&Qs[(w * 16 + c) * 72 + kt * 32 + quad * 8];
#pragma unroll
        for (int j = 0; j < 12; j++) {
            bf16x8 bv = *(const bf16x8*)&Ks[(j * 16 + c) * 72 + kt * 32 + quad * 8];
            acc[j] = MFMA_BF16(af, bv, acc[j]);
        }
    }
    __syncthreads();   // all Qs/Ks reads done before P overlay writes

    // ---- mask + scale + wave-local softmax (rows quad*4+r of this wave)
    const float scale = 0.16832169878499658f;   // (0.1*ln32+1)/sqrt(64)
    const int igb = i0 + w * 16 + quad * 4;
    float rmax[4] = {-3.0e4f, -3.0e4f, -3.0e4f, -3.0e4f};
#pragma unroll
    for (int j = 0; j < 12; j++) {
        int jg = k0 + j * 16 + c;
#pragma unroll
        for (int r = 0; r < 4; r++) {
            int ig = igb + r;
            bool ok = (jg >= 0) && (jg <= ig) && (ig - jg < 128);
            float vv = ok ? acc[j][r] * scale : -3.0e4f;
            acc[j][r] = vv;
            rmax[r] = fmaxf(rmax[r], vv);
        }
    }
#pragma unroll
    for (int off = 1; off < 16; off <<= 1)
#pragma unroll
        for (int r = 0; r < 4; r++)
            rmax[r] = fmaxf(rmax[r], __shfl_xor(rmax[r], off));

    float rs[4] = {0.f, 0.f, 0.f, 0.f};
#pragma unroll
    for (int j = 0; j < 12; j++)
#pragma unroll
        for (int r = 0; r < 4; r++) {
            float e = __expf(acc[j][r] - rmax[r]);
            acc[j][r] = e;
            rs[r] += e;
        }
#pragma unroll
    for (int off = 1; off < 16; off <<= 1)
#pragma unroll
        for (int r = 0; r < 4; r++)
            rs[r] += __shfl_xor(rs[r], off);

    // rowfac = sigmoid(lse - sink) / rowsum   (diagonal valid => rs >= 1)
    float rowfac[4];
    {
        float sk = (float)sinks[h];
#pragma unroll
        for (int r = 0; r < 4; r++) {
            float s = fmaxf(rs[r], 1e-20f);
            float lse = rmax[r] + __logf(s);
            rowfac[r] = 1.f / ((1.f + __expf(sk - lse)) * s);
        }
    }

    // ---- write P (bf16 probabilities), wave-local rows
#pragma unroll
    for (int j = 0; j < 12; j++)
#pragma unroll
        for (int r = 0; r < 4; r++)
            P[(w * 16 + quad * 4 + r) * 208 + j * 16 + c] = (__bf16)acc[j][r];
    __syncthreads();

    // ---- PV: wave w -> its 16 q rows x 64 dims, K=192
    f32x4 acc2[4];
#pragma unroll
    for (int jd = 0; jd < 4; jd++) acc2[jd] = (f32x4){0.f, 0.f, 0.f, 0.f};
#pragma unroll
    for (int kt = 0; kt < 6; kt++) {
        bf16x8 a = *(const bf16x8*)&P[(w * 16 + c) * 208 + kt * 32 + quad * 8];
#pragma unroll
        for (int jd = 0; jd < 4; jd++) {
            bf16x8 b = *(const bf16x8*)&Vt[(jd * 16 + c) * 208 + kt * 32 + quad * 8];
            acc2[jd] = MFMA_BF16(a, b, acc2[jd]);
        }
    }
#pragma unroll
    for (int jd = 0; jd < 4; jd++)
#pragma unroll
        for (int r = 0; r < 4; r++) {
            int qr = w * 16 + quad * 4 + r;
            q[(size_t)(i0 + qr) * 4096 + h * 64 + jd * 16 + c] =
                (__bf16)(acc2[jd][r] * rowfac[r]);
        }
}

// ---------------------------------------------------------------------------
extern "C" void kernel_launch(void* const* d_in, const int* in_sizes, int n_in,
                              void* d_out, int out_size, void* d_ws, size_t ws_size,
                              hipStream_t stream) {
    char* ws = (char*)d_ws;
    __bf16* qb   = (__bf16*)(ws);                        // 2048*4096 bf16 = 16 MB
    __bf16* kb   = (__bf16*)(ws + 16777216);             // 2048*512  bf16 =  2 MB
    __bf16* vb   = (__bf16*)(ws + 16777216 + 2097152);   // 2048*512  bf16 =  2 MB
    int*    flag = (int*)   (ws + 16777216 + 2097152 + 2097152);

    detect_kernel<<<1, 64, 0, stream>>>((const unsigned short*)d_in[0], flag);

    // ---- pipeline A: bf16 buffers (want=0)
    {
        const __bf16* x    = (const __bf16*)d_in[0];
        const __bf16* rope = (const __bf16*)d_in[1];
        const __bf16* wq   = (const __bf16*)d_in[2];
        const __bf16* bq   = (const __bf16*)d_in[3];
        const __bf16* wk   = (const __bf16*)d_in[4];
        const __bf16* bk   = (const __bf16*)d_in[5];
        const __bf16* wv   = (const __bf16*)d_in[6];
        const __bf16* bv   = (const __bf16*)d_in[7];
        const __bf16* wo   = (const __bf16*)d_in[8];
        const __bf16* bo   = (const __bf16*)d_in[9];
        const __bf16* sk   = (const __bf16*)d_in[10];
        qkv_kernel<__bf16><<<dim3(16, 40), 256, 0, stream>>>(
            x, wq, bq, wk, bk, wv, bv, qb, kb, vb, flag, 0);
        rope_kernel<__bf16><<<2304, 256, 0, stream>>>(qb, kb, rope, flag, 0);
        attn_kernel<__bf16><<<dim3(32, 64), 256, 0, stream>>>(qb, kb, vb, sk, flag, 0);
        oproj_kernel<__bf16><<<dim3(16, 23), 256, 0, stream>>>(
            qb, wo, bo, (__bf16*)d_out, flag, 0);
    }

    // ---- pipeline B: f32 buffers (want=1)
    {
        const float* x    = (const float*)d_in[0];
        const float* rope = (const float*)d_in[1];
        const float* wq   = (const float*)d_in[2];
        const float* bq   = (const float*)d_in[3];
        const float* wk   = (const float*)d_in[4];
        const float* bk   = (const float*)d_in[5];
        const float* wv   = (const float*)d_in[6];
        const float* bv   = (const float*)d_in[7];
        const float* wo   = (const float*)d_in[8];
        const float* bo   = (const float*)d_in[9];
        const float* sk   = (const float*)d_in[10];
        qkv_kernel<float><<<dim3(16, 40), 256, 0, stream>>>(
            x, wq, bq, wk, bk, wv, bv, qb, kb, vb, flag, 1);
        rope_kernel<float><<<2304, 256, 0, stream>>>(qb, kb, rope, flag, 1);
        attn_kernel<float><<<dim3(32, 64), 256, 0, stream>>>(qb, kb, vb, sk, flag, 1);
        oproj_kernel<float><<<dim3(16, 23), 256, 0, stream>>>(
            qb, wo, bo, (float*)d_out, flag, 1);
    }
}

// Round 4
// 409.265 us; speedup vs baseline: 1.3398x; 1.3398x over previous
//
#include <hip/hip_runtime.h>
#include <hip/hip_bf16.h>
#include <math.h>

// ---------------------------------------------------------------------------
// Attention_17231408791684: x->QKV (bias) -> RoPE -> sliding-window(128)
// causal attention w/ sinks -> O-proj (bias).
// B=1 S=2048 DIM=2880 NH=64 NKV=8 HD=64.  d_in/d_out are FLOAT32 (verified
// round 3: f32 pipeline was the active one). Intermediates bf16.
// Round 4: pre-convert f32 operands to bf16 (one mem-bound pass), then
// m97-style GEMMs (global_load_lds width=16, 128x128 tile, 2-barrier K-loop).
// ---------------------------------------------------------------------------

typedef __bf16 bf16x8 __attribute__((ext_vector_type(8)));
typedef float  f32x4  __attribute__((ext_vector_type(4)));

#define MFMA_BF16(a,b,c) __builtin_amdgcn_mfma_f32_16x16x32_bf16((a),(b),(c),0,0,0)

__device__ __forceinline__ void gld_lds16(const void* g, void* l) {
    // async global->LDS, 16B/lane; LDS dest must be wave-uniform base + lane*16
    __builtin_amdgcn_global_load_lds(
        (__attribute__((address_space(1))) void*)(g),
        (__attribute__((address_space(3))) void*)(l), 16, 0, 0);
}

__device__ __forceinline__ bf16x8 ld8f(const float* p) {
    f32x4 a = *(const f32x4*)p;
    f32x4 b = *(const f32x4*)(p + 4);
    bf16x8 r;
#pragma unroll
    for (int t = 0; t < 4; t++) { r[t] = (__bf16)a[t]; r[t + 4] = (__bf16)b[t]; }
    return r;
}

// ---------------------------------------------------------------------------
// f32 -> bf16 conversion of {x, wq, wk, wv, wo} into one contiguous bf16
// region. 8 elements/thread, exact grid (15840 blocks x 256).
// Segment element offsets: x 0, wq 5898240, wk 17694720, wv 19169280,
// wo 20643840, end 32440320.
// ---------------------------------------------------------------------------
__global__ __launch_bounds__(256) void convert_kernel(
    const float* __restrict__ x,  const float* __restrict__ wq,
    const float* __restrict__ wk, const float* __restrict__ wv,
    const float* __restrict__ wo, __bf16* __restrict__ dst)
{
    long e = ((long)blockIdx.x * 256 + threadIdx.x) * 8;
    const float* src; long off;
    if      (e <  5898240L) { src = x;  off = e; }
    else if (e < 17694720L) { src = wq; off = e -  5898240L; }
    else if (e < 19169280L) { src = wk; off = e - 17694720L; }
    else if (e < 20643840L) { src = wv; off = e - 19169280L; }
    else                    { src = wo; off = e - 20643840L; }
    *(bf16x8*)(dst + e) = ld8f(src + off);
}

// ---------------------------------------------------------------------------
// NT GEMM (m97 structure): C[M,N] = A[M,K]*W[N,K]^T + bias. bf16 in, f32 acc.
// 128x128 tile, BK=32, 256 threads (4 waves as 2x2 of 64x64 sub-tiles).
// Staging via global_load_lds width=16; LDS tiles unpadded 128x32 (4096 elem)
// in exact lane order (gld_lds constraint). 2-barrier K-loop.
// ---------------------------------------------------------------------------
template <typename TO>
__device__ __forceinline__ void gemm_block(
    const __bf16* __restrict__ A, const __bf16* __restrict__ W,
    const float* __restrict__ bias, TO* __restrict__ C,
    int N, int K, int m0, int n0, __bf16* As, __bf16* Bs)
{
    const int tid  = threadIdx.x;
    const int lane = tid & 63;
    const int wv   = tid >> 6;
    const int wm   = (wv >> 1) * 64;
    const int wn   = (wv & 1) * 64;
    const int quad = lane >> 4;
    const int c    = lane & 15;

    // staging: thread t covers row t/4 (of 64), cols (t&3)*8 .. +8
    const int arow = tid >> 2;
    const int acol = (tid & 3) * 8;

    int br0 = n0 + arow;      if (br0 > N - 1) br0 = N - 1;   // N tail clamp
    int br1 = n0 + 64 + arow; if (br1 > N - 1) br1 = N - 1;
    const __bf16* pa0 = A + (size_t)(m0 + arow) * K + acol;
    const __bf16* pa1 = A + (size_t)(m0 + 64 + arow) * K + acol;
    const __bf16* pb0 = W + (size_t)br0 * K + acol;
    const __bf16* pb1 = W + (size_t)br1 * K + acol;

    f32x4 acc[4][4];
#pragma unroll
    for (int i = 0; i < 4; i++)
#pragma unroll
        for (int j = 0; j < 4; j++) acc[i][j] = (f32x4){0.f, 0.f, 0.f, 0.f};

    for (int kk = 0; kk < K; kk += 32) {
        gld_lds16(pa0 + kk, As + tid * 8);          // rows 0..63
        gld_lds16(pa1 + kk, As + 2048 + tid * 8);   // rows 64..127
        gld_lds16(pb0 + kk, Bs + tid * 8);
        gld_lds16(pb1 + kk, Bs + 2048 + tid * 8);
        __syncthreads();                            // drain gld_lds, tile ready
        bf16x8 af[4], bfv[4];
#pragma unroll
        for (int i = 0; i < 4; i++)
            af[i] = *(const bf16x8*)&As[(wm + i * 16 + c) * 32 + quad * 8];
#pragma unroll
        for (int j = 0; j < 4; j++)
            bfv[j] = *(const bf16x8*)&Bs[(wn + j * 16 + c) * 32 + quad * 8];
#pragma unroll
        for (int i = 0; i < 4; i++)
#pragma unroll
            for (int j = 0; j < 4; j++)
                acc[i][j] = MFMA_BF16(af[i], bfv[j], acc[i][j]);
        __syncthreads();                            // reads done before next store
    }

    // epilogue: D row = quad*4+r, col = c (m89-verified layout); f32 bias
#pragma unroll
    for (int j = 0; j < 4; j++) {
        int col = n0 + wn + j * 16 + c;
        if (col >= N) continue;
        float bv = bias[col];
#pragma unroll
        for (int i = 0; i < 4; i++) {
            int row = m0 + wm + i * 16 + quad * 4;
#pragma unroll
            for (int r = 0; r < 4; r++)
                C[(size_t)(row + r) * N + col] = (TO)(acc[i][j][r] + bv);
        }
    }
}

// Fused QKV: grid (16, 40); by<32 -> q (N=4096), by<36 -> k, else v (N=512)
__global__ __launch_bounds__(256) void qkv_kernel(
    const __bf16* __restrict__ x,
    const __bf16* __restrict__ wq, const float* __restrict__ bq,
    const __bf16* __restrict__ wk, const float* __restrict__ bk,
    const __bf16* __restrict__ wv, const float* __restrict__ bv,
    __bf16* __restrict__ qo, __bf16* __restrict__ ko, __bf16* __restrict__ vo)
{
    __shared__ __align__(16) __bf16 As[4096], Bs[4096];
    const int by = blockIdx.y;
    const __bf16 *W; const float* bias; __bf16* C; int N, n0;
    if (by < 32)      { W = wq; bias = bq; C = qo; N = 4096; n0 = by * 128; }
    else if (by < 36) { W = wk; bias = bk; C = ko; N = 512;  n0 = (by - 32) * 128; }
    else              { W = wv; bias = bv; C = vo; N = 512;  n0 = (by - 36) * 128; }
    gemm_block<__bf16>(x, W, bias, C, N, 2880, blockIdx.x * 128, n0, As, Bs);
}

// O-proj: grid (16, 23): out[2048,2880] = AB[2048,4096] * wo[2880,4096]^T + bo
__global__ __launch_bounds__(256) void oproj_kernel(
    const __bf16* __restrict__ a, const __bf16* __restrict__ w,
    const float* __restrict__ b, float* __restrict__ c)
{
    __shared__ __align__(16) __bf16 As[4096], Bs[4096];
    gemm_block<float>(a, w, b, c, 2880, 4096,
                      blockIdx.x * 128, blockIdx.y * 128, As, Bs);
}

// ---------------------------------------------------------------------------
// RoPE in-place on qb[2048,64,64] / kb[2048,8,64] (bf16). rope cache is f32:
// rope[s] = [cos(64) | sin(64)], halves duplicated.
// thread = (s, head 0..71, dgroup 0..3): d in [d0,d0+8) and [d0+32,d0+40)
// ---------------------------------------------------------------------------
__global__ __launch_bounds__(256) void rope_kernel(
    __bf16* __restrict__ qb, __bf16* __restrict__ kb,
    const float* __restrict__ rope)
{
    int idx  = blockIdx.x * 256 + threadIdx.x;   // 2048*72*4, exact grid
    int dg   = idx & 3;
    int head = (idx >> 2) % 72;
    int s    = (idx >> 2) / 72;
    __bf16* p = (head < 64) ? (qb + (size_t)s * 4096 + head * 64)
                            : (kb + (size_t)s * 512 + (size_t)(head - 64) * 64);
    int d0 = dg * 8;
    bf16x8 x1 = *(bf16x8*)(p + d0);
    bf16x8 x2 = *(bf16x8*)(p + d0 + 32);
    const float* rc = rope + (size_t)s * 128 + d0;
    bf16x8 o1, o2;
#pragma unroll
    for (int t = 0; t < 8; t++) {
        float cc = rc[t], si = rc[64 + t];
        float a = (float)x1[t], b = (float)x2[t];
        o1[t] = (__bf16)(a * cc - b * si);
        o2[t] = (__bf16)(b * cc + a * si);
    }
    *(bf16x8*)(p + d0)      = o1;
    *(bf16x8*)(p + d0 + 32) = o2;
}

// ---------------------------------------------------------------------------
// Attention, IN-PLACE on q. block = (64-query tile, head); wave w owns q rows
// [w*16,w*16+16) x all 192 staged keys (k0 = i0-128 covers the window).
// Softmax stats wave-local via shfl over the 16-lane c group.
// LDS: Qs[64][72]@0, Ks[192][72]@9216, Vt[64][208]@36864; P overlays @0.
// ---------------------------------------------------------------------------
__global__ __launch_bounds__(256) void attn_kernel(
    __bf16* __restrict__ q, const __bf16* __restrict__ k,
    const __bf16* __restrict__ v, const float* __restrict__ sinks,
    float /*unused*/ = 0.f)
{
    __shared__ __align__(16) char smem[63488];
    __bf16* Qs = (__bf16*)smem;                 // [64][72]
    __bf16* Ks = (__bf16*)(smem + 9216);        // [192][72]
    __bf16* Vt = (__bf16*)(smem + 36864);       // [64][208]
    __bf16* P  = (__bf16*)smem;                 // [64][208] overlay (post-QK^T)

    const int tid = threadIdx.x, lane = tid & 63, w = tid >> 6;
    const int quad = lane >> 4, c = lane & 15;
    const int i0 = blockIdx.x * 64;
    const int h  = blockIdx.y;
    const int kvh = h >> 3;
    const int k0 = i0 - 128;

    // ---- stage Q, K (stride 72) and V transposed (stride 208)
    {
        const int row = tid >> 3;           // 0..31
        const int col = (tid & 7) * 8;      // 0..56
#pragma unroll
        for (int it = 0; it < 2; it++) {
            int r2 = row + it * 32;
            bf16x8 t = *(const bf16x8*)(q + (size_t)(i0 + r2) * 4096 + h * 64 + col);
            *(bf16x8*)&Qs[r2 * 72 + col] = t;
        }
#pragma unroll
        for (int it = 0; it < 6; it++) {
            int r2 = row + it * 32;
            int j = k0 + r2; if (j < 0) j = 0;
            bf16x8 t = *(const bf16x8*)(k + (size_t)j * 512 + kvh * 64 + col);
            *(bf16x8*)&Ks[r2 * 72 + col] = t;
        }
        const int vrow = tid & 31;
        const int d0 = (tid >> 5) * 8;
#pragma unroll
        for (int it = 0; it < 6; it++) {
            int r2 = vrow + it * 32;
            int j = k0 + r2; if (j < 0) j = 0;
            bf16x8 t = *(const bf16x8*)(v + (size_t)j * 512 + kvh * 64 + d0);
#pragma unroll
            for (int u = 0; u < 8; u++) Vt[(d0 + u) * 208 + r2] = t[u];
        }
    }
    __syncthreads();

    // ---- QK^T: wave w -> its 16 q rows x 192 keys (12 key tiles)
    f32x4 acc[12];
#pragma unroll
    for (int j = 0; j < 12; j++) acc[j] = (f32x4){0.f, 0.f, 0.f, 0.f};
#pragma unroll
    for (int kt = 0; kt < 2; kt++) {
        bf16x8 af = *(const bf16x8*)&Qs[(w * 16 + c) * 72 + kt * 32 + quad * 8];
#pragma unroll
        for (int j = 0; j < 12; j++) {
            bf16x8 bv = *(const bf16x8*)&Ks[(j * 16 + c) * 72 + kt * 32 + quad * 8];
            acc[j] = MFMA_BF16(af, bv, acc[j]);
        }
    }
    __syncthreads();   // all Qs/Ks reads done before P overlay writes

    // ---- mask + scale + wave-local softmax (rows quad*4+r of this wave)
    const float scale = 0.16832169878499658f;   // (0.1*ln32+1)/sqrt(64)
    const int igb = i0 + w * 16 + quad * 4;
    float rmax[4] = {-3.0e4f, -3.0e4f, -3.0e4f, -3.0e4f};
#pragma unroll
    for (int j = 0; j < 12; j++) {
        int jg = k0 + j * 16 + c;
#pragma unroll
        for (int r = 0; r < 4; r++) {
            int ig = igb + r;
            bool ok = (jg >= 0) && (jg <= ig) && (ig - jg < 128);
            float vv = ok ? acc[j][r] * scale : -3.0e4f;
            acc[j][r] = vv;
            rmax[r] = fmaxf(rmax[r], vv);
        }
    }
#pragma unroll
    for (int off = 1; off < 16; off <<= 1)
#pragma unroll
        for (int r = 0; r < 4; r++)
            rmax[r] = fmaxf(rmax[r], __shfl_xor(rmax[r], off));

    float rs[4] = {0.f, 0.f, 0.f, 0.f};
#pragma unroll
    for (int j = 0; j < 12; j++)
#pragma unroll
        for (int r = 0; r < 4; r++) {
            float e = __expf(acc[j][r] - rmax[r]);
            acc[j][r] = e;
            rs[r] += e;
        }
#pragma unroll
    for (int off = 1; off < 16; off <<= 1)
#pragma unroll
        for (int r = 0; r < 4; r++)
            rs[r] += __shfl_xor(rs[r], off);

    // rowfac = sigmoid(lse - sink) / rowsum   (diagonal valid => rs >= 1)
    float rowfac[4];
    {
        float sk = sinks[h];
#pragma unroll
        for (int r = 0; r < 4; r++) {
            float s = fmaxf(rs[r], 1e-20f);
            float lse = rmax[r] + __logf(s);
            rowfac[r] = 1.f / ((1.f + __expf(sk - lse)) * s);
        }
    }

    // ---- write P (bf16 probabilities), wave-local rows
#pragma unroll
    for (int j = 0; j < 12; j++)
#pragma unroll
        for (int r = 0; r < 4; r++)
            P[(w * 16 + quad * 4 + r) * 208 + j * 16 + c] = (__bf16)acc[j][r];
    __syncthreads();

    // ---- PV: wave w -> its 16 q rows x 64 dims, K=192
    f32x4 acc2[4];
#pragma unroll
    for (int jd = 0; jd < 4; jd++) acc2[jd] = (f32x4){0.f, 0.f, 0.f, 0.f};
#pragma unroll
    for (int kt = 0; kt < 6; kt++) {
        bf16x8 a = *(const bf16x8*)&P[(w * 16 + c) * 208 + kt * 32 + quad * 8];
#pragma unroll
        for (int jd = 0; jd < 4; jd++) {
            bf16x8 b = *(const bf16x8*)&Vt[(jd * 16 + c) * 208 + kt * 32 + quad * 8];
            acc2[jd] = MFMA_BF16(a, b, acc2[jd]);
        }
    }
#pragma unroll
    for (int jd = 0; jd < 4; jd++)
#pragma unroll
        for (int r = 0; r < 4; r++) {
            int qr = w * 16 + quad * 4 + r;
            q[(size_t)(i0 + qr) * 4096 + h * 64 + jd * 16 + c] =
                (__bf16)(acc2[jd][r] * rowfac[r]);
        }
}

// ---------------------------------------------------------------------------
extern "C" void kernel_launch(void* const* d_in, const int* in_sizes, int n_in,
                              void* d_out, int out_size, void* d_ws, size_t ws_size,
                              hipStream_t stream) {
    const float* x    = (const float*)d_in[0];
    const float* rope = (const float*)d_in[1];
    const float* wq   = (const float*)d_in[2];
    const float* bq   = (const float*)d_in[3];
    const float* wk   = (const float*)d_in[4];
    const float* bk   = (const float*)d_in[5];
    const float* wv   = (const float*)d_in[6];
    const float* bv   = (const float*)d_in[7];
    const float* wo   = (const float*)d_in[8];
    const float* bo   = (const float*)d_in[9];
    const float* sk   = (const float*)d_in[10];
    float* out = (float*)d_out;

    // bf16 workspace layout (element offsets into one __bf16 region):
    //   xb 0, wqb 5898240, wkb 17694720, wvb 19169280, wob 20643840,
    //   qb 32440320, kb 40828928, vb 41877504, end 42926080 (~85.9 MB)
    __bf16* wsb = (__bf16*)d_ws;
    __bf16* xb  = wsb;
    __bf16* wqb = wsb +  5898240L;
    __bf16* wkb = wsb + 17694720L;
    __bf16* wvb = wsb + 19169280L;
    __bf16* wob = wsb + 20643840L;
    __bf16* qb  = wsb + 32440320L;
    __bf16* kb  = wsb + 40828928L;
    __bf16* vb  = wsb + 41877504L;

    convert_kernel<<<15840, 256, 0, stream>>>(x, wq, wk, wv, wo, xb);
    qkv_kernel<<<dim3(16, 40), 256, 0, stream>>>(xb, wqb, bq, wkb, bk, wvb, bv,
                                                 qb, kb, vb);
    rope_kernel<<<2304, 256, 0, stream>>>(qb, kb, rope);
    attn_kernel<<<dim3(32, 64), 256, 0, stream>>>(qb, kb, vb, sk);
    oproj_kernel<<<dim3(16, 23), 256, 0, stream>>>(qb, wob, bo, out);
}

// Round 5
// 349.318 us; speedup vs baseline: 1.5697x; 1.1716x over previous
//
#include <hip/hip_runtime.h>
#include <hip/hip_bf16.h>
#include <math.h>

// ---------------------------------------------------------------------------
// Attention_17231408791684: x->QKV (bias) -> RoPE -> sliding-window(128)
// causal attention w/ sinks -> O-proj (bias).
// B=1 S=2048 DIM=2880 NH=64 NKV=8 HD=64.  d_in/d_out are FLOAT32.
// Round 5: BK=64 K-loop (halve barrier count) + split-K=2 oproj (736 blocks)
// with bf16 partials + reduce epilogue.
// ---------------------------------------------------------------------------

typedef __bf16 bf16x8 __attribute__((ext_vector_type(8)));
typedef float  f32x4  __attribute__((ext_vector_type(4)));

#define MFMA_BF16(a,b,c) __builtin_amdgcn_mfma_f32_16x16x32_bf16((a),(b),(c),0,0,0)

__device__ __forceinline__ void gld_lds16(const void* g, void* l) {
    // async global->LDS, 16B/lane; LDS dest = wave-uniform base + lane*16
    __builtin_amdgcn_global_load_lds(
        (__attribute__((address_space(1))) void*)(g),
        (__attribute__((address_space(3))) void*)(l), 16, 0, 0);
}

__device__ __forceinline__ bf16x8 ld8f(const float* p) {
    f32x4 a = *(const f32x4*)p;
    f32x4 b = *(const f32x4*)(p + 4);
    bf16x8 r;
#pragma unroll
    for (int t = 0; t < 4; t++) { r[t] = (__bf16)a[t]; r[t + 4] = (__bf16)b[t]; }
    return r;
}

// ---------------------------------------------------------------------------
// f32 -> bf16 conversion of {x, wq, wk, wv, wo} into one contiguous bf16
// region. 8 elements/thread, exact grid (15840 x 256).
// Offsets: x 0, wq 5898240, wk 17694720, wv 19169280, wo 20643840, end 32440320
// ---------------------------------------------------------------------------
__global__ __launch_bounds__(256) void convert_kernel(
    const float* __restrict__ x,  const float* __restrict__ wq,
    const float* __restrict__ wk, const float* __restrict__ wv,
    const float* __restrict__ wo, __bf16* __restrict__ dst)
{
    long e = ((long)blockIdx.x * 256 + threadIdx.x) * 8;
    const float* src; long off;
    if      (e <  5898240L) { src = x;  off = e; }
    else if (e < 17694720L) { src = wq; off = e -  5898240L; }
    else if (e < 19169280L) { src = wk; off = e - 17694720L; }
    else if (e < 20643840L) { src = wv; off = e - 19169280L; }
    else                    { src = wo; off = e - 20643840L; }
    *(bf16x8*)(dst + e) = ld8f(src + off);
}

// ---------------------------------------------------------------------------
// NT GEMM, BK=64: C[M,N] = A[M,Ks]*W[N,Ks]^T (+bias) over k in [kBeg,kEnd).
// 128x128 tile, 256 threads (4 waves as 2x2 of 64x64). LDS = [2][128][32]
// per operand (two 32-col sub-tiles; keeps the proven 64B-stride fragment
// reads AND the gld_lds lane-order constraint). 32 MFMA per barrier pair.
// bias==nullptr -> no bias (split-K partial). TO = __bf16 or float.
// ---------------------------------------------------------------------------
template <typename TO>
__device__ __forceinline__ void gemm_block64(
    const __bf16* __restrict__ A, const __bf16* __restrict__ W,
    const float* __restrict__ bias, TO* __restrict__ C,
    int N, int Ks, int kBeg, int kEnd, int m0, int n0,
    __bf16* As, __bf16* Bs)
{
    const int tid  = threadIdx.x;
    const int lane = tid & 63;
    const int wv   = tid >> 6;
    const int wm   = (wv >> 1) * 64;
    const int wn   = (wv & 1) * 64;
    const int quad = lane >> 4;
    const int c    = lane & 15;

    // staging: thread t covers row t/4 (0..63), cols (t&3)*8 .. +8
    const int srow = tid >> 2;
    const int scol = (tid & 3) * 8;

    int br0 = n0 + srow;      if (br0 > N - 1) br0 = N - 1;   // N tail clamp
    int br1 = n0 + 64 + srow; if (br1 > N - 1) br1 = N - 1;
    const __bf16* pa0 = A + (size_t)(m0 + srow) * Ks + scol;
    const __bf16* pa1 = A + (size_t)(m0 + 64 + srow) * Ks + scol;
    const __bf16* pb0 = W + (size_t)br0 * Ks + scol;
    const __bf16* pb1 = W + (size_t)br1 * Ks + scol;

    f32x4 acc[4][4];
#pragma unroll
    for (int i = 0; i < 4; i++)
#pragma unroll
        for (int j = 0; j < 4; j++) acc[i][j] = (f32x4){0.f, 0.f, 0.f, 0.f};

    for (int kk = kBeg; kk < kEnd; kk += 64) {
        // sub-tile 0: cols kk..kk+31 ; sub-tile 1: cols kk+32..kk+63
        gld_lds16(pa0 + kk,      As + tid * 8);
        gld_lds16(pa1 + kk,      As + 2048 + tid * 8);
        gld_lds16(pa0 + kk + 32, As + 4096 + tid * 8);
        gld_lds16(pa1 + kk + 32, As + 6144 + tid * 8);
        gld_lds16(pb0 + kk,      Bs + tid * 8);
        gld_lds16(pb1 + kk,      Bs + 2048 + tid * 8);
        gld_lds16(pb0 + kk + 32, Bs + 4096 + tid * 8);
        gld_lds16(pb1 + kk + 32, Bs + 6144 + tid * 8);
        __syncthreads();                       // drain gld_lds, tile ready
        for (int kt = 0; kt < 2; kt++) {
            bf16x8 af[4], bfv[4];
#pragma unroll
            for (int i = 0; i < 4; i++)
                af[i] = *(const bf16x8*)&As[kt * 4096 + (wm + i * 16 + c) * 32 + quad * 8];
#pragma unroll
            for (int j = 0; j < 4; j++)
                bfv[j] = *(const bf16x8*)&Bs[kt * 4096 + (wn + j * 16 + c) * 32 + quad * 8];
#pragma unroll
            for (int i = 0; i < 4; i++)
#pragma unroll
                for (int j = 0; j < 4; j++)
                    acc[i][j] = MFMA_BF16(af[i], bfv[j], acc[i][j]);
        }
        __syncthreads();                       // reads done before next store
    }

    // epilogue: D row = quad*4+r, col = c (m89-verified layout)
#pragma unroll
    for (int j = 0; j < 4; j++) {
        int col = n0 + wn + j * 16 + c;
        if (col >= N) continue;
        float bv = bias ? bias[col] : 0.0f;
#pragma unroll
        for (int i = 0; i < 4; i++) {
            int row = m0 + wm + i * 16 + quad * 4;
#pragma unroll
            for (int r = 0; r < 4; r++)
                C[(size_t)(row + r) * N + col] = (TO)(acc[i][j][r] + bv);
        }
    }
}

// Fused QKV: grid (16, 40); by<32 -> q (N=4096), by<36 -> k, else v (N=512)
__global__ __launch_bounds__(256, 3) void qkv_kernel(
    const __bf16* __restrict__ x,
    const __bf16* __restrict__ wq, const float* __restrict__ bq,
    const __bf16* __restrict__ wk, const float* __restrict__ bk,
    const __bf16* __restrict__ wv, const float* __restrict__ bv,
    __bf16* __restrict__ qo, __bf16* __restrict__ ko, __bf16* __restrict__ vo)
{
    __shared__ __align__(16) __bf16 As[8192], Bs[8192];
    const int by = blockIdx.y;
    const __bf16 *W; const float* bias; __bf16* C; int N, n0;
    if (by < 32)      { W = wq; bias = bq; C = qo; N = 4096; n0 = by * 128; }
    else if (by < 36) { W = wk; bias = bk; C = ko; N = 512;  n0 = (by - 32) * 128; }
    else              { W = wv; bias = bv; C = vo; N = 512;  n0 = (by - 36) * 128; }
    gemm_block64<__bf16>(x, W, bias, C, N, 2880, 0, 2880,
                         blockIdx.x * 128, n0, As, Bs);
}

// O-proj split-K partial: grid (16, 23, 2); half z covers k in [z*2048,(z+1)*2048)
__global__ __launch_bounds__(256, 3) void oproj_kernel(
    const __bf16* __restrict__ a, const __bf16* __restrict__ w,
    __bf16* __restrict__ p0, __bf16* __restrict__ p1)
{
    __shared__ __align__(16) __bf16 As[8192], Bs[8192];
    const int z = blockIdx.z;
    __bf16* C = z ? p1 : p0;
    gemm_block64<__bf16>(a, w, nullptr, C, 2880, 4096, z * 2048, (z + 1) * 2048,
                         blockIdx.x * 128, blockIdx.y * 128, As, Bs);
}

// out[e] = p0[e] + p1[e] + bias[col]; 8 elems/thread, grid 2880 x 256 exact.
__global__ __launch_bounds__(256) void reduce_kernel(
    const __bf16* __restrict__ p0, const __bf16* __restrict__ p1,
    const float* __restrict__ bo, float* __restrict__ out)
{
    long e = ((long)blockIdx.x * 256 + threadIdx.x) * 8;
    int col = (int)(e % 2880L);          // 2880 % 8 == 0: no row crossing
    bf16x8 a = *(const bf16x8*)(p0 + e);
    bf16x8 b = *(const bf16x8*)(p1 + e);
    f32x4 o0, o1;
#pragma unroll
    for (int t = 0; t < 4; t++) {
        o0[t] = (float)a[t]     + (float)b[t]     + bo[col + t];
        o1[t] = (float)a[4 + t] + (float)b[4 + t] + bo[col + 4 + t];
    }
    *(f32x4*)(out + e)     = o0;
    *(f32x4*)(out + e + 4) = o1;
}

// ---------------------------------------------------------------------------
// RoPE in-place on qb[2048,64,64] / kb[2048,8,64] (bf16). rope cache f32:
// rope[s] = [cos(64) | sin(64)], halves duplicated.
// ---------------------------------------------------------------------------
__global__ __launch_bounds__(256) void rope_kernel(
    __bf16* __restrict__ qb, __bf16* __restrict__ kb,
    const float* __restrict__ rope)
{
    int idx  = blockIdx.x * 256 + threadIdx.x;   // 2048*72*4, exact grid
    int dg   = idx & 3;
    int head = (idx >> 2) % 72;
    int s    = (idx >> 2) / 72;
    __bf16* p = (head < 64) ? (qb + (size_t)s * 4096 + head * 64)
                            : (kb + (size_t)s * 512 + (size_t)(head - 64) * 64);
    int d0 = dg * 8;
    bf16x8 x1 = *(bf16x8*)(p + d0);
    bf16x8 x2 = *(bf16x8*)(p + d0 + 32);
    const float* rc = rope + (size_t)s * 128 + d0;
    bf16x8 o1, o2;
#pragma unroll
    for (int t = 0; t < 8; t++) {
        float cc = rc[t], si = rc[64 + t];
        float a = (float)x1[t], b = (float)x2[t];
        o1[t] = (__bf16)(a * cc - b * si);
        o2[t] = (__bf16)(b * cc + a * si);
    }
    *(bf16x8*)(p + d0)      = o1;
    *(bf16x8*)(p + d0 + 32) = o2;
}

// ---------------------------------------------------------------------------
// Attention, IN-PLACE on q. block = (64-query tile, head); wave w owns q rows
// [w*16,w*16+16) x all 192 staged keys (k0 = i0-128 covers the window).
// Softmax stats wave-local via shfl over the 16-lane c group.
// LDS: Qs[64][72]@0, Ks[192][72]@9216, Vt[64][208]@36864; P overlays @0.
// ---------------------------------------------------------------------------
__global__ __launch_bounds__(256) void attn_kernel(
    __bf16* __restrict__ q, const __bf16* __restrict__ k,
    const __bf16* __restrict__ v, const float* __restrict__ sinks)
{
    __shared__ __align__(16) char smem[63488];
    __bf16* Qs = (__bf16*)smem;                 // [64][72]
    __bf16* Ks = (__bf16*)(smem + 9216);        // [192][72]
    __bf16* Vt = (__bf16*)(smem + 36864);       // [64][208]
    __bf16* P  = (__bf16*)smem;                 // [64][208] overlay (post-QK^T)

    const int tid = threadIdx.x, lane = tid & 63, w = tid >> 6;
    const int quad = lane >> 4, c = lane & 15;
    const int i0 = blockIdx.x * 64;
    const int h  = blockIdx.y;
    const int kvh = h >> 3;
    const int k0 = i0 - 128;

    // ---- stage Q, K (stride 72) and V transposed (stride 208)
    {
        const int row = tid >> 3;           // 0..31
        const int col = (tid & 7) * 8;      // 0..56
#pragma unroll
        for (int it = 0; it < 2; it++) {
            int r2 = row + it * 32;
            bf16x8 t = *(const bf16x8*)(q + (size_t)(i0 + r2) * 4096 + h * 64 + col);
            *(bf16x8*)&Qs[r2 * 72 + col] = t;
        }
#pragma unroll
        for (int it = 0; it < 6; it++) {
            int r2 = row + it * 32;
            int j = k0 + r2; if (j < 0) j = 0;
            bf16x8 t = *(const bf16x8*)(k + (size_t)j * 512 + kvh * 64 + col);
            *(bf16x8*)&Ks[r2 * 72 + col] = t;
        }
        const int vrow = tid & 31;
        const int d0 = (tid >> 5) * 8;
#pragma unroll
        for (int it = 0; it < 6; it++) {
            int r2 = vrow + it * 32;
            int j = k0 + r2; if (j < 0) j = 0;
            bf16x8 t = *(const bf16x8*)(v + (size_t)j * 512 + kvh * 64 + d0);
#pragma unroll
            for (int u = 0; u < 8; u++) Vt[(d0 + u) * 208 + r2] = t[u];
        }
    }
    __syncthreads();

    // ---- QK^T: wave w -> its 16 q rows x 192 keys (12 key tiles)
    f32x4 acc[12];
#pragma unroll
    for (int j = 0; j < 12; j++) acc[j] = (f32x4){0.f, 0.f, 0.f, 0.f};
#pragma unroll
    for (int kt = 0; kt < 2; kt++) {
        bf16x8 af = *(const bf16x8*)&Qs[(w * 16 + c) * 72 + kt * 32 + quad * 8];
#pragma unroll
        for (int j = 0; j < 12; j++) {
            bf16x8 bv = *(const bf16x8*)&Ks[(j * 16 + c) * 72 + kt * 32 + quad * 8];
            acc[j] = MFMA_BF16(af, bv, acc[j]);
        }
    }
    __syncthreads();   // all Qs/Ks reads done before P overlay writes

    // ---- mask + scale + wave-local softmax (rows quad*4+r of this wave)
    const float scale = 0.16832169878499658f;   // (0.1*ln32+1)/sqrt(64)
    const int igb = i0 + w * 16 + quad * 4;
    float rmax[4] = {-3.0e4f, -3.0e4f, -3.0e4f, -3.0e4f};
#pragma unroll
    for (int j = 0; j < 12; j++) {
        int jg = k0 + j * 16 + c;
#pragma unroll
        for (int r = 0; r < 4; r++) {
            int ig = igb + r;
            bool ok = (jg >= 0) && (jg <= ig) && (ig - jg < 128);
            float vv = ok ? acc[j][r] * scale : -3.0e4f;
            acc[j][r] = vv;
            rmax[r] = fmaxf(rmax[r], vv);
        }
    }
#pragma unroll
    for (int off = 1; off < 16; off <<= 1)
#pragma unroll
        for (int r = 0; r < 4; r++)
            rmax[r] = fmaxf(rmax[r], __shfl_xor(rmax[r], off));

    float rs[4] = {0.f, 0.f, 0.f, 0.f};
#pragma unroll
    for (int j = 0; j < 12; j++)
#pragma unroll
        for (int r = 0; r < 4; r++) {
            float e = __expf(acc[j][r] - rmax[r]);
            acc[j][r] = e;
            rs[r] += e;
        }
#pragma unroll
    for (int off = 1; off < 16; off <<= 1)
#pragma unroll
        for (int r = 0; r < 4; r++)
            rs[r] += __shfl_xor(rs[r], off);

    // rowfac = sigmoid(lse - sink) / rowsum   (diagonal valid => rs >= 1)
    float rowfac[4];
    {
        float sk = sinks[h];
#pragma unroll
        for (int r = 0; r < 4; r++) {
            float s = fmaxf(rs[r], 1e-20f);
            float lse = rmax[r] + __logf(s);
            rowfac[r] = 1.f / ((1.f + __expf(sk - lse)) * s);
        }
    }

    // ---- write P (bf16 probabilities), wave-local rows
#pragma unroll
    for (int j = 0; j < 12; j++)
#pragma unroll
        for (int r = 0; r < 4; r++)
            P[(w * 16 + quad * 4 + r) * 208 + j * 16 + c] = (__bf16)acc[j][r];
    __syncthreads();

    // ---- PV: wave w -> its 16 q rows x 64 dims, K=192
    f32x4 acc2[4];
#pragma unroll
    for (int jd = 0; jd < 4; jd++) acc2[jd] = (f32x4){0.f, 0.f, 0.f, 0.f};
#pragma unroll
    for (int kt = 0; kt < 6; kt++) {
        bf16x8 a = *(const bf16x8*)&P[(w * 16 + c) * 208 + kt * 32 + quad * 8];
#pragma unroll
        for (int jd = 0; jd < 4; jd++) {
            bf16x8 b = *(const bf16x8*)&Vt[(jd * 16 + c) * 208 + kt * 32 + quad * 8];
            acc2[jd] = MFMA_BF16(a, b, acc2[jd]);
        }
    }
#pragma unroll
    for (int jd = 0; jd < 4; jd++)
#pragma unroll
        for (int r = 0; r < 4; r++) {
            int qr = w * 16 + quad * 4 + r;
            q[(size_t)(i0 + qr) * 4096 + h * 64 + jd * 16 + c] =
                (__bf16)(acc2[jd][r] * rowfac[r]);
        }
}

// ---------------------------------------------------------------------------
extern "C" void kernel_launch(void* const* d_in, const int* in_sizes, int n_in,
                              void* d_out, int out_size, void* d_ws, size_t ws_size,
                              hipStream_t stream) {
    const float* x    = (const float*)d_in[0];
    const float* rope = (const float*)d_in[1];
    const float* wq   = (const float*)d_in[2];
    const float* bq   = (const float*)d_in[3];
    const float* wk   = (const float*)d_in[4];
    const float* bk   = (const float*)d_in[5];
    const float* wv   = (const float*)d_in[6];
    const float* bv   = (const float*)d_in[7];
    const float* wo   = (const float*)d_in[8];
    const float* bo   = (const float*)d_in[9];
    const float* sk   = (const float*)d_in[10];
    float* out = (float*)d_out;

    // bf16 workspace layout (element offsets): xb 0, wqb 5898240,
    // wkb 17694720, wvb 19169280, wob 20643840, qb 32440320, kb 40828928,
    // vb 41877504, end 42926080 (~85.9 MB).
    // part0/part1 (oproj split-K partials, 5898240 each) REUSE the xb/wqb
    // region — dead after qkv_kernel has consumed it.
    __bf16* wsb = (__bf16*)d_ws;
    __bf16* xb  = wsb;
    __bf16* wqb = wsb +  5898240L;
    __bf16* wkb = wsb + 17694720L;
    __bf16* wvb = wsb + 19169280L;
    __bf16* wob = wsb + 20643840L;
    __bf16* qb  = wsb + 32440320L;
    __bf16* kb  = wsb + 40828928L;
    __bf16* vb  = wsb + 41877504L;
    __bf16* p0  = wsb;                 // overlay, post-qkv
    __bf16* p1  = wsb +  5898240L;

    convert_kernel<<<15840, 256, 0, stream>>>(x, wq, wk, wv, wo, xb);
    qkv_kernel<<<dim3(16, 40), 256, 0, stream>>>(xb, wqb, bq, wkb, bk, wvb, bv,
                                                 qb, kb, vb);
    rope_kernel<<<2304, 256, 0, stream>>>(qb, kb, rope);
    attn_kernel<<<dim3(32, 64), 256, 0, stream>>>(qb, kb, vb, sk);
    oproj_kernel<<<dim3(16, 23, 2), 256, 0, stream>>>(qb, wob, p0, p1);
    reduce_kernel<<<2880, 256, 0, stream>>>(p0, p1, bo, out);
}